// Round 2
// baseline (192.735 us; speedup 1.0000x reference)
//
#include <hip/hip_runtime.h>
#include <hip/hip_bf16.h>
#include <math.h>

#define N_NODES 50000
#define M_NEIGH 16
#define HID     64
#define BATCH   4

typedef float fvec4 __attribute__((ext_vector_type(4)));

// One wave (64 lanes) per node n.
// lane = b*16 + q : b in [0,4) batches, q in [0,16) float4-quads of H=64.
// All lanes of the wave share the same 16 neighbor indices (wave-uniform,
// scalarized via readfirstlane -> s_load path). Gather per m: 4 contiguous
// 256B row segments, 16B/lane, fully coalesced.
__global__ __launch_bounds__(256) void pool_max_kernel(
    const fvec4* __restrict__ x,      // [B, N, 16] fvec4
    const int*   __restrict__ index,  // [N, 16]
    fvec4*       __restrict__ out)    // [B, N, 16] fvec4
{
    const int wave_in_block = __builtin_amdgcn_readfirstlane(threadIdx.x >> 6);
    const int n = blockIdx.x * 4 + wave_in_block;
    if (n >= N_NODES) return;

    const int lane = threadIdx.x & 63;
    const int b = lane >> 4;   // batch
    const int q = lane & 15;   // fvec4 quad within the H=64 row

    const fvec4* xb = x + (size_t)b * N_NODES * (HID / 4);

    // Load the 16 indices for this node (wave-uniform).
    const int* idx_ptr = index + (size_t)n * M_NEIGH;
    int idx[M_NEIGH];
#pragma unroll
    for (int m = 0; m < M_NEIGH; ++m) idx[m] = idx_ptr[m];

    fvec4 acc = (fvec4){-INFINITY, -INFINITY, -INFINITY, -INFINITY};
#pragma unroll
    for (int m = 0; m < M_NEIGH; ++m) {
        const int r = idx[m];
        fvec4 v;
        if (r < N_NODES) {               // wave-uniform branch
            v = xb[(size_t)r * (HID / 4) + q];
        } else {                          // padded zero row
            v = (fvec4){0.f, 0.f, 0.f, 0.f};
        }
        acc.x = fmaxf(acc.x, v.x);
        acc.y = fmaxf(acc.y, v.y);
        acc.z = fmaxf(acc.z, v.z);
        acc.w = fmaxf(acc.w, v.w);
    }

    // Streaming store; written exactly once -> keep L2 for x gathers.
    __builtin_nontemporal_store(acc, &out[((size_t)b * N_NODES + n) * (HID / 4) + q]);
}

extern "C" void kernel_launch(void* const* d_in, const int* in_sizes, int n_in,
                              void* d_out, int out_size, void* d_ws, size_t ws_size,
                              hipStream_t stream) {
    const fvec4* x   = (const fvec4*)d_in[0];
    const int*   idx = (const int*)d_in[1];
    fvec4*       out = (fvec4*)d_out;

    // One wave per node, 4 waves (256 threads) per block.
    const int blocks = (N_NODES + 3) / 4;  // 12500
    pool_max_kernel<<<blocks, 256, 0, stream>>>(x, idx, out);
}

// Round 3
// 166.314 us; speedup vs baseline: 1.1589x; 1.1589x over previous
//
#include <hip/hip_runtime.h>
#include <hip/hip_bf16.h>
#include <math.h>

#define N_NODES 50000
#define M_NEIGH 16
#define HID     64
#define BATCH   4

typedef float fvec4 __attribute__((ext_vector_type(4)));

// Batch-per-XCD partitioning: batch = blockIdx.x & 3. Workgroups round-robin
// across the 8 XCDs on linear blockIdx, so batch b lands on XCDs {b, b+4}.
// Each XCD's 4 MB L2 then only serves one 12.8 MB batch slab of x instead of
// the whole 51.2 MB — cuts L2 miss traffic (R2: FETCH_SIZE 371 MB).
//
// Wave layout: lane = node_sub*16 + q. Each wave handles 4 nodes of one
// batch; each 16-lane group covers one node's H=64 row (16 fvec4 quads).
// Gather per m: 4 distinct contiguous 256 B segments per instruction.
__global__ __launch_bounds__(256) void pool_max_kernel(
    const fvec4* __restrict__ x,      // [B, N, 16] fvec4
    const int*   __restrict__ index,  // [N, 16]
    fvec4*       __restrict__ out)    // [B, N, 16] fvec4
{
    const int batch = blockIdx.x & 3;          // XCD affinity
    const int group = blockIdx.x >> 2;         // 0..3124, 16 nodes each
    const int wave  = threadIdx.x >> 6;        // 0..3
    const int lane  = threadIdx.x & 63;
    const int q     = lane & 15;               // quad within H row
    const int n     = group * 16 + wave * 4 + (lane >> 4);

    const fvec4* xb = x + (size_t)batch * N_NODES * (HID / 4);
    const int* idx_ptr = index + (size_t)n * M_NEIGH;

    // Preload all 16 indices (16-lane-group uniform) so the 16 gathers can
    // all be in flight together.
    int idx[M_NEIGH];
#pragma unroll
    for (int m = 0; m < M_NEIGH; ++m) idx[m] = idx_ptr[m];

    fvec4 acc = (fvec4){-INFINITY, -INFINITY, -INFINITY, -INFINITY};
#pragma unroll
    for (int m = 0; m < M_NEIGH; ++m) {
        const int r  = idx[m];
        const int rc = r < N_NODES ? r : 0;    // clamped (branchless load)
        fvec4 v = xb[(size_t)rc * (HID / 4) + q];
        if (r >= N_NODES) v = (fvec4){0.f, 0.f, 0.f, 0.f};  // pad row -> 0
        acc.x = fmaxf(acc.x, v.x);
        acc.y = fmaxf(acc.y, v.y);
        acc.z = fmaxf(acc.z, v.z);
        acc.w = fmaxf(acc.w, v.w);
    }

    // Written exactly once -> streaming store, keep L2 for x gathers.
    __builtin_nontemporal_store(acc,
        &out[((size_t)batch * N_NODES + n) * (HID / 4) + q]);
}

extern "C" void kernel_launch(void* const* d_in, const int* in_sizes, int n_in,
                              void* d_out, int out_size, void* d_ws, size_t ws_size,
                              hipStream_t stream) {
    const fvec4* x   = (const fvec4*)d_in[0];
    const int*   idx = (const int*)d_in[1];
    fvec4*       out = (fvec4*)d_out;

    // 16 nodes per block per batch: 3125 groups * 4 batches = 12500 blocks.
    const int blocks = (N_NODES / 16) * BATCH;  // 12500 (50000 % 16 == 0)
    pool_max_kernel<<<blocks, 256, 0, stream>>>(x, idx, out);
}

// Round 4
// 147.363 us; speedup vs baseline: 1.3079x; 1.1286x over previous
//
#include <hip/hip_runtime.h>
#include <hip/hip_bf16.h>
#include <math.h>

#define N_NODES 50000
#define M_NEIGH 16
#define HID     64
#define BATCH   4

typedef float fvec4 __attribute__((ext_vector_type(4)));

// XCD partitioning over batch x H-half: p = blockIdx & 7 -> batch = p&3,
// half = p>>2. Workgroups round-robin across the 8 XCDs on linear blockIdx,
// so XCD p only gathers from batch b's half-row slab: 50000 * 128 B = 6.4 MB
// (vs 12.8 MB in R3 -> FETCH 282 MB). Halving the working set should raise
// the L2 hit rate further.
//
// Wave layout: lane = node_sub*8 + q8. Each wave covers 8 nodes; each 8-lane
// group covers one node's 32-float half-row (8 fvec4 quads = 128 B
// contiguous per gather -> coalesced, 2 cache lines per node).
__global__ __launch_bounds__(256) void pool_max_kernel(
    const fvec4* __restrict__ x,      // [B, N, 16] fvec4
    const int*   __restrict__ index,  // [N, 16]
    fvec4*       __restrict__ out)    // [B, N, 16] fvec4
{
    const int p     = blockIdx.x & 7;          // XCD partition id
    const int batch = p & 3;
    const int half  = p >> 2;                  // which 32-float half of H
    const int group = blockIdx.x >> 3;         // 32 nodes per group
    const int wave  = threadIdx.x >> 6;        // 0..3
    const int lane  = threadIdx.x & 63;
    const int q8    = lane & 7;                // quad within half-row
    const int n     = group * 32 + wave * 8 + (lane >> 3);
    if (n >= N_NODES) return;

    const fvec4* xb = x + ((size_t)batch * N_NODES) * (HID / 4) + half * 8;
    const int* idx_ptr = index + (size_t)n * M_NEIGH;

    int idx[M_NEIGH];
#pragma unroll
    for (int m = 0; m < M_NEIGH; ++m) idx[m] = idx_ptr[m];

    fvec4 acc = (fvec4){-INFINITY, -INFINITY, -INFINITY, -INFINITY};
#pragma unroll
    for (int m = 0; m < M_NEIGH; ++m) {
        const int r  = idx[m];
        const int rc = r < N_NODES ? r : 0;    // clamped (branchless load)
        fvec4 v = xb[(size_t)rc * (HID / 4) + q8];
        if (r >= N_NODES) v = (fvec4){0.f, 0.f, 0.f, 0.f};  // pad row -> 0
        acc.x = fmaxf(acc.x, v.x);
        acc.y = fmaxf(acc.y, v.y);
        acc.z = fmaxf(acc.z, v.z);
        acc.w = fmaxf(acc.w, v.w);
    }

    // Written exactly once -> streaming store, keep L2 for x gathers.
    __builtin_nontemporal_store(acc,
        &out[((size_t)batch * N_NODES + n) * (HID / 4) + half * 8 + q8]);
}

extern "C" void kernel_launch(void* const* d_in, const int* in_sizes, int n_in,
                              void* d_out, int out_size, void* d_ws, size_t ws_size,
                              hipStream_t stream) {
    const fvec4* x   = (const fvec4*)d_in[0];
    const int*   idx = (const int*)d_in[1];
    fvec4*       out = (fvec4*)d_out;

    // 32 nodes per block per partition: ceil(50000/32)=1563 groups * 8 = 12504.
    const int groups = (N_NODES + 31) / 32;
    pool_max_kernel<<<groups * 8, 256, 0, stream>>>(x, idx, out);
}